// Round 10
// baseline (232.904 us; speedup 1.0000x reference)
//
#include <hip/hip_runtime.h>

#define EPSI 1e-5f

typedef __attribute__((ext_vector_type(8))) short bf16x8;
typedef __attribute__((ext_vector_type(4))) float f32x4;

__device__ __forceinline__ float lrelu(float x) { return x > 0.f ? x : 0.01f * x; }

// float -> bf16 bits, round-to-nearest-even (header-free)
__device__ __forceinline__ unsigned short f2bf(float x) {
    unsigned int u = __float_as_uint(x);
    return (unsigned short)((u + 0x7fffu + ((u >> 16) & 1u)) >> 16);
}
// bf16 pair (packed in uint) -> floats
__device__ __forceinline__ float bflo(unsigned int v) { return __uint_as_float(v << 16); }
__device__ __forceinline__ float bfhi(unsigned int v) { return __uint_as_float(v & 0xFFFF0000u); }

__device__ __forceinline__ bf16x8 pack8(float4 a, float4 b) {
    union { unsigned short u[8]; bf16x8 v; } p;
    p.u[0] = f2bf(a.x); p.u[1] = f2bf(a.y); p.u[2] = f2bf(a.z); p.u[3] = f2bf(a.w);
    p.u[4] = f2bf(b.x); p.u[5] = f2bf(b.y); p.u[6] = f2bf(b.z); p.u[7] = f2bf(b.w);
    return p.v;
}

// Block-wide sum of (a,b). blockDim.x == 256.
__device__ __forceinline__ float2 block_reduce_sum2(float a, float b) {
    #pragma unroll
    for (int off = 1; off < 64; off <<= 1) {
        a += __shfl_xor(a, off, 64);
        b += __shfl_xor(b, off, 64);
    }
    __shared__ float lds[8];
    const int t = threadIdx.x;
    if ((t & 63) == 0) { lds[2 * (t >> 6)] = a; lds[2 * (t >> 6) + 1] = b; }
    __syncthreads();
    a = lds[0] + lds[2] + lds[4] + lds[6];
    b = lds[1] + lds[3] + lds[5] + lds[7];
    return make_float2(a, b);
}

// ---------------- K1: conv1(3->16) + IN + lrelu, single pass, bf16 out -----------
// grid: B=256 blocks, 1024 threads, 4 px/thread, acc[16][4] in VGPRs.
__global__ __launch_bounds__(1024, 1) void k1_conv_in(const float* __restrict__ x,
                                                      const float* __restrict__ w1,
                                                      unsigned short* __restrict__ h1) {
    const int n = blockIdx.x;
    const int t = threadIdx.x;
    __shared__ float red[16][16][2]; // [wave][co][s1/s2]
    __shared__ float msc[16][2];     // [co][mean/scale]
    const float* xn = x + (size_t)n * 49152;
    float acc[16][4];
    #pragma unroll
    for (int j = 0; j < 16; ++j)
        #pragma unroll
        for (int q = 0; q < 4; ++q) acc[j][q] = 0.f;
    #pragma unroll 1
    for (int ic = 0; ic < 3; ++ic) {
        const float* p = xn + ic * 16384;
        float2 v0[4], v1[4];
        #pragma unroll
        for (int q = 0; q < 4; ++q) {
            const int idx = t + 1024 * q;
            const int oy = idx >> 6, ox = idx & 63;
            v0[q] = ((const float2*)(p + (2 * oy) * 128))[ox];
            v1[q] = ((const float2*)(p + (2 * oy + 1) * 128))[ox];
        }
        #pragma unroll
        for (int j = 0; j < 16; ++j) {
            const float4 wv = *(const float4*)(w1 + j * 12 + ic * 4);  // uniform -> SGPR
            #pragma unroll
            for (int q = 0; q < 4; ++q)
                acc[j][q] += v0[q].x * wv.x + v0[q].y * wv.y + v1[q].x * wv.z + v1[q].y * wv.w;
        }
    }
    const int w = t >> 6, l = t & 63;
    #pragma unroll
    for (int j = 0; j < 16; ++j) {
        float s1 = acc[j][0] + acc[j][1] + acc[j][2] + acc[j][3];
        float s2 = acc[j][0] * acc[j][0] + acc[j][1] * acc[j][1] +
                   acc[j][2] * acc[j][2] + acc[j][3] * acc[j][3];
        #pragma unroll
        for (int off = 1; off < 64; off <<= 1) {
            s1 += __shfl_xor(s1, off, 64);
            s2 += __shfl_xor(s2, off, 64);
        }
        if (l == 0) { red[w][j][0] = s1; red[w][j][1] = s2; }
    }
    __syncthreads();
    if (t < 16) {
        float s1 = 0.f, s2 = 0.f;
        #pragma unroll
        for (int ww = 0; ww < 16; ++ww) { s1 += red[ww][t][0]; s2 += red[ww][t][1]; }
        const float mean = s1 * (1.f / 4096.f);
        const float var = s2 * (1.f / 4096.f) - mean * mean;
        msc[t][0] = mean; msc[t][1] = rsqrtf(var + EPSI);
    }
    __syncthreads();
    unsigned short* on = h1 + (size_t)n * 65536;
    #pragma unroll
    for (int j = 0; j < 16; ++j) {
        const float mean = msc[j][0], sc = msc[j][1];
        #pragma unroll
        for (int q = 0; q < 4; ++q)
            on[j * 4096 + t + 1024 * q] = f2bf(lrelu((acc[j][q] - mean) * sc));
    }
}

// ---------------- K2: conv2(16->32) + IN + lrelu, LDS-staged bf16 ----------------
// grid: B=256 blocks, 512 threads, 2 px/thread, acc[32][2]. Input sample staged in
// LDS in 2x 64KB stages; compiler re-reads (loop distribution) hit LDS, not HBM.
__global__ __launch_bounds__(512, 1) void k2_conv_in(const unsigned short* __restrict__ h1,
                                                     const float* __restrict__ w2,
                                                     unsigned short* __restrict__ h2) {
    const int n = blockIdx.x;
    const int t = threadIdx.x;
    __shared__ unsigned short xs[8 * 4096];  // 64KB: 8 planes per stage
    __shared__ float red[8][32][2];
    __shared__ float msc[32][2];
    const unsigned short* h1n = h1 + (size_t)n * 65536;
    float acc[32][2];
    #pragma unroll
    for (int j = 0; j < 32; ++j) { acc[j][0] = 0.f; acc[j][1] = 0.f; }
    const int oy0 = t >> 5, ox0 = t & 31;
    const int oy1 = (t + 512) >> 5, ox1 = (t + 512) & 31;
    #pragma unroll 1
    for (int s = 0; s < 2; ++s) {
        __syncthreads();
        #pragma unroll
        for (int i = 0; i < 8; ++i)
            ((uint4*)xs)[t + 512 * i] = ((const uint4*)(h1n + s * 32768))[t + 512 * i];
        __syncthreads();
        #pragma unroll 1
        for (int ic = 0; ic < 8; ++ic) {
            const unsigned short* pl = xs + ic * 4096;
            const unsigned int a0 = *(const unsigned int*)(pl + (2 * oy0) * 64 + 2 * ox0);
            const unsigned int a1 = *(const unsigned int*)(pl + (2 * oy0 + 1) * 64 + 2 * ox0);
            const unsigned int b0 = *(const unsigned int*)(pl + (2 * oy1) * 64 + 2 * ox1);
            const unsigned int b1 = *(const unsigned int*)(pl + (2 * oy1 + 1) * 64 + 2 * ox1);
            const float f00 = bflo(a0), f01 = bfhi(a0), f02 = bflo(a1), f03 = bfhi(a1);
            const float f10 = bflo(b0), f11 = bfhi(b0), f12 = bflo(b1), f13 = bfhi(b1);
            #pragma unroll
            for (int j = 0; j < 32; ++j) {
                const float4 wv = *(const float4*)(w2 + j * 144 + (s * 8 + ic) * 4);  // SGPR
                acc[j][0] += f00 * wv.x + f01 * wv.y + f02 * wv.z + f03 * wv.w;
                acc[j][1] += f10 * wv.x + f11 * wv.y + f12 * wv.z + f13 * wv.w;
            }
        }
    }
    const int w = t >> 6, l = t & 63;
    #pragma unroll
    for (int j = 0; j < 32; ++j) {
        float s1 = acc[j][0] + acc[j][1];
        float s2 = acc[j][0] * acc[j][0] + acc[j][1] * acc[j][1];
        #pragma unroll
        for (int off = 1; off < 64; off <<= 1) {
            s1 += __shfl_xor(s1, off, 64);
            s2 += __shfl_xor(s2, off, 64);
        }
        if (l == 0) { red[w][j][0] = s1; red[w][j][1] = s2; }
    }
    __syncthreads();
    if (t < 32) {
        float s1 = 0.f, s2 = 0.f;
        #pragma unroll
        for (int ww = 0; ww < 8; ++ww) { s1 += red[ww][t][0]; s2 += red[ww][t][1]; }
        const float mean = s1 * (1.f / 1024.f);
        const float var = s2 * (1.f / 1024.f) - mean * mean;
        msc[t][0] = mean; msc[t][1] = rsqrtf(var + EPSI);
    }
    __syncthreads();
    unsigned short* on = h2 + (size_t)n * 32768;
    #pragma unroll
    for (int j = 0; j < 32; ++j) {
        const float mean = msc[j][0], sc = msc[j][1];
        on[j * 1024 + t]       = f2bf(lrelu((acc[j][0] - mean) * sc));
        on[j * 1024 + t + 512] = f2bf(lrelu((acc[j][1] - mean) * sc));
    }
}

// ---------------- K3: conv3(32->64) + IN + lrelu, LDS-staged, 4 passes x 16 co ---
// grid: B=256 blocks, 256 threads, 1 px/thread. Full input sample (64KB) in LDS.
__global__ __launch_bounds__(256, 1) void k3_conv_in(const unsigned short* __restrict__ h2,
                                                     const float* __restrict__ w3,
                                                     unsigned short* __restrict__ h3) {
    const int n = blockIdx.x;
    const int t = threadIdx.x;
    __shared__ unsigned short xs[32 * 1024];  // 64KB
    __shared__ float red[4][16][2];
    __shared__ float msc[16][2];
    const unsigned short* h2n = h2 + (size_t)n * 32768;
    #pragma unroll
    for (int i = 0; i < 16; ++i)
        ((uint4*)xs)[t + 256 * i] = ((const uint4*)h2n)[t + 256 * i];
    __syncthreads();
    const int oy = t >> 4, ox = t & 15;
    const int w = t >> 6, l = t & 63;
    unsigned short* on = h3 + (size_t)n * 16384;
    #pragma unroll 1
    for (int p = 0; p < 4; ++p) {
        float acc[16];
        #pragma unroll
        for (int j = 0; j < 16; ++j) acc[j] = 0.f;
        #pragma unroll 1
        for (int ic = 0; ic < 32; ++ic) {
            const unsigned short* pl = xs + ic * 1024;
            const unsigned int a0 = *(const unsigned int*)(pl + (2 * oy) * 32 + 2 * ox);
            const unsigned int a1 = *(const unsigned int*)(pl + (2 * oy + 1) * 32 + 2 * ox);
            const float f0 = bflo(a0), f1 = bfhi(a0), f2 = bflo(a1), f3 = bfhi(a1);
            #pragma unroll
            for (int j = 0; j < 16; ++j) {
                const float4 wv = *(const float4*)(w3 + (size_t)(p * 16 + j) * 128 + ic * 4);
                acc[j] += f0 * wv.x + f1 * wv.y + f2 * wv.z + f3 * wv.w;
            }
        }
        #pragma unroll
        for (int j = 0; j < 16; ++j) {
            float s1 = acc[j], s2 = acc[j] * acc[j];
            #pragma unroll
            for (int off = 1; off < 64; off <<= 1) {
                s1 += __shfl_xor(s1, off, 64);
                s2 += __shfl_xor(s2, off, 64);
            }
            if (l == 0) { red[w][j][0] = s1; red[w][j][1] = s2; }
        }
        __syncthreads();
        if (t < 16) {
            const float s1 = red[0][t][0] + red[1][t][0] + red[2][t][0] + red[3][t][0];
            const float s2 = red[0][t][1] + red[1][t][1] + red[2][t][1] + red[3][t][1];
            const float mean = s1 * (1.f / 256.f);
            const float var = s2 * (1.f / 256.f) - mean * mean;
            msc[t][0] = mean; msc[t][1] = rsqrtf(var + EPSI);
        }
        __syncthreads();
        #pragma unroll
        for (int j = 0; j < 16; ++j)
            on[(p * 16 + j) * 256 + t] = f2bf(lrelu((acc[j] - msc[j][0]) * msc[j][1]));
    }
}

// ---------------- K4: conv4(64->128) + IN + lrelu, LDS-staged, bf16 out ----------
// grid: B=256 blocks, 256 threads. Input sample (32KB) in LDS. Wave w: lane = px,
// 4 passes x 8 co (co = w*32 + p*8 + jj). IN reduce = wave shuffle (plane = 64 px).
__global__ __launch_bounds__(256, 1) void k4_conv_in(const unsigned short* __restrict__ h3,
                                                     const float* __restrict__ w4,
                                                     unsigned short* __restrict__ h4) {
    const int n = blockIdx.x;
    const int t = threadIdx.x;
    __shared__ unsigned short xs[64 * 256];  // 32KB
    const unsigned short* h3n = h3 + (size_t)n * 16384;
    #pragma unroll
    for (int i = 0; i < 8; ++i)
        ((uint4*)xs)[t + 256 * i] = ((const uint4*)h3n)[t + 256 * i];
    __syncthreads();
    const int w = __builtin_amdgcn_readfirstlane(t >> 6);
    const int l = t & 63;
    const int oy = l >> 3, ox = l & 7;
    unsigned short* on = h4 + (size_t)n * 8192;
    #pragma unroll 1
    for (int p = 0; p < 4; ++p) {
        const float* wbase = w4 + (size_t)(w * 32 + p * 8) * 256;
        float acc[8];
        #pragma unroll
        for (int jj = 0; jj < 8; ++jj) acc[jj] = 0.f;
        #pragma unroll 1
        for (int ic = 0; ic < 64; ++ic) {
            const unsigned short* pl = xs + ic * 256;
            const unsigned int a0 = *(const unsigned int*)(pl + (2 * oy) * 16 + 2 * ox);
            const unsigned int a1 = *(const unsigned int*)(pl + (2 * oy + 1) * 16 + 2 * ox);
            const float f0 = bflo(a0), f1 = bfhi(a0), f2 = bflo(a1), f3 = bfhi(a1);
            #pragma unroll
            for (int jj = 0; jj < 8; ++jj) {
                const float4 wv = *(const float4*)(wbase + jj * 256 + ic * 4);  // SGPR
                acc[jj] += f0 * wv.x + f1 * wv.y + f2 * wv.z + f3 * wv.w;
            }
        }
        #pragma unroll
        for (int jj = 0; jj < 8; ++jj) {
            float s1 = acc[jj], s2 = acc[jj] * acc[jj];
            #pragma unroll
            for (int off = 1; off < 64; off <<= 1) {
                s1 += __shfl_xor(s1, off, 64);
                s2 += __shfl_xor(s2, off, 64);
            }
            const float mean = s1 * (1.f / 64.f);
            const float var = s2 * (1.f / 64.f) - mean * mean;
            const float sc = rsqrtf(var + EPSI);
            on[(w * 32 + p * 8 + jj) * 64 + l] = f2bf(lrelu((acc[jj] - mean) * sc));
        }
    }
}

// ---------------- K5: FC1 bf16 MFMA split-K GEMM (W converted in-staging) --------
// C[256,1024] = A[256,8192](bf16) x W[1024,8192]^T(fp32->bf16 on the fly).
// BM=BN=128, BK=64, SK=16 (K-chunk 512): grid = 16 tiles x 16 sk = 256 blocks.
__global__ __launch_bounds__(256, 2) void k5_fc1(const unsigned short* __restrict__ A,
                                                 const float* __restrict__ Wf,
                                                 float* __restrict__ Cp) {
    __shared__ unsigned short As[128 * 72];
    __shared__ unsigned short Bs[128 * 72];
    const int t = threadIdx.x;
    const int sk = blockIdx.x >> 4;          // 0..15
    const int tile = blockIdx.x & 15;        // mt*8 + nt
    const int mt = tile >> 3, nt = tile & 7;
    const int m0 = mt * 128, n0 = nt * 128;
    const int w = t >> 6, l = t & 63;
    const int wm = (w >> 1) * 64, wn = (w & 1) * 64;
    const int lr16 = l & 15, lk8 = (l >> 4) * 8;   // frag row / k-base (guide §3)
    const int srow = t >> 3, scol = (t & 7) * 8;   // staging row / col
    f32x4 acc[4][4];
    const f32x4 z = {0.f, 0.f, 0.f, 0.f};
    #pragma unroll
    for (int f = 0; f < 4; ++f)
        #pragma unroll
        for (int g = 0; g < 4; ++g) acc[f][g] = z;
    const int kbeg = sk * 512;
    #pragma unroll 1
    for (int kt = 0; kt < 8; ++kt) {
        const int kc = kbeg + kt * 64;
        bf16x8 av[4], bv[4];
        #pragma unroll
        for (int i = 0; i < 4; ++i) {
            av[i] = *(const bf16x8*)(A + (size_t)(m0 + srow + 32 * i) * 8192 + kc + scol);
            const float4 w0 = *(const float4*)(Wf + (size_t)(n0 + srow + 32 * i) * 8192 + kc + scol);
            const float4 w1 = *(const float4*)(Wf + (size_t)(n0 + srow + 32 * i) * 8192 + kc + scol + 4);
            bv[i] = pack8(w0, w1);
        }
        __syncthreads();   // previous tile's frag reads complete
        #pragma unroll
        for (int i = 0; i < 4; ++i) {
            *(bf16x8*)&As[(srow + 32 * i) * 72 + scol] = av[i];
            *(bf16x8*)&Bs[(srow + 32 * i) * 72 + scol] = bv[i];
        }
        __syncthreads();   // tile staged
        #pragma unroll
        for (int ks = 0; ks < 2; ++ks) {
            bf16x8 af[4], bfr[4];
            #pragma unroll
            for (int f = 0; f < 4; ++f)
                af[f] = *(const bf16x8*)&As[(wm + f * 16 + lr16) * 72 + ks * 32 + lk8];
            #pragma unroll
            for (int g = 0; g < 4; ++g)
                bfr[g] = *(const bf16x8*)&Bs[(wn + g * 16 + lr16) * 72 + ks * 32 + lk8];
            #pragma unroll
            for (int f = 0; f < 4; ++f)
                #pragma unroll
                for (int g = 0; g < 4; ++g)
                    acc[f][g] = __builtin_amdgcn_mfma_f32_16x16x32_bf16(af[f], bfr[g], acc[f][g], 0, 0, 0);
        }
    }
    // C/D layout (guide §3, m89-verified): col = l&15, row = (l>>4)*4 + reg
    const int orow = (l >> 4) * 4, ocol = l & 15;
    #pragma unroll
    for (int f = 0; f < 4; ++f) {
        #pragma unroll
        for (int g = 0; g < 4; ++g) {
            #pragma unroll
            for (int j = 0; j < 4; ++j) {
                const int m = m0 + wm + f * 16 + orow + j;
                const int n = n0 + wn + g * 16 + ocol;
                Cp[((size_t)sk * 256 + m) * 1024 + n] = acc[f][g][j];
            }
        }
    }
}

// ---------------- K6: fused split-K reduce + bias + lrelu + FC2 ------------------
__global__ __launch_bounds__(256) void k6_fc2(const float* __restrict__ Cp,
                                              const float* __restrict__ bias,
                                              const float* __restrict__ w,
                                              const float* __restrict__ b,
                                              float* __restrict__ out) {
    const int n = blockIdx.x, t = threadIdx.x;
    float part = 0.f;
    #pragma unroll
    for (int i = 0; i < 4; ++i) {
        const int nn = t + 256 * i;
        float s = 0.f;
        #pragma unroll
        for (int sk = 0; sk < 16; ++sk)
            s += Cp[((size_t)sk * 256 + n) * 1024 + nn];
        part += lrelu(s + bias[nn]) * w[nn];
    }
    const float2 red = block_reduce_sum2(part, 0.f);
    if (t == 0) out[n] = red.x + b[0];
}

extern "C" void kernel_launch(void* const* d_in, const int* in_sizes, int n_in,
                              void* d_out, int out_size, void* d_ws, size_t ws_size,
                              hipStream_t stream) {
    (void)in_sizes; (void)n_in; (void)out_size; (void)ws_size;
    const float* x    = (const float*)d_in[0];
    // labels (d_in[1]) and conv biases (d_in[3,5,7,9]) cancel exactly under InstanceNorm
    const float* w1   = (const float*)d_in[2];
    const float* w2   = (const float*)d_in[4];
    const float* w3   = (const float*)d_in[6];
    const float* w4   = (const float*)d_in[8];
    const float* fcw1 = (const float*)d_in[10];
    const float* fcb1 = (const float*)d_in[11];
    const float* fcw2 = (const float*)d_in[12];
    const float* fcb2 = (const float*)d_in[13];
    float* out = (float*)d_out;
    float* bufA = (float*)d_ws;                    // 16.7M floats (67 MB)
    float* bufB = bufA + 16777216;                 //  8.4M floats (33 MB)
    unsigned short* h1 = (unsigned short*)bufA;    // 16.7M bf16 (33.5 MB)
    unsigned short* h2 = (unsigned short*)bufB;    //  8.4M bf16 (16.8 MB)
    unsigned short* h3 = (unsigned short*)bufA;    //  4.2M bf16 (h1 dead)
    unsigned short* h4 = (unsigned short*)bufB;    //  2.1M bf16 (h2 dead)
    float* Cp = bufA;                              // 16*256*1024 fp32 (h3 dead at k5)
    k1_conv_in<<<256, 1024, 0, stream>>>(x, w1, h1);
    k2_conv_in<<<256, 512, 0, stream>>>(h1, w2, h2);
    k3_conv_in<<<256, 256, 0, stream>>>(h2, w3, h3);
    k4_conv_in<<<256, 256, 0, stream>>>(h3, w4, h4);
    k5_fc1<<<256, 256, 0, stream>>>(h4, fcw1, Cp);
    k6_fc2<<<256, 256, 0, stream>>>(Cp, fcb1, fcw2, fcb2, out);
}

// Round 11
// 135.059 us; speedup vs baseline: 1.7245x; 1.7245x over previous
//
#include <hip/hip_runtime.h>

#define EPSI 1e-5f

typedef __attribute__((ext_vector_type(8))) short bf16x8;
typedef __attribute__((ext_vector_type(4))) float f32x4;

__device__ __forceinline__ float lrelu(float x) { return x > 0.f ? x : 0.01f * x; }

// float -> bf16 bits, round-to-nearest-even (header-free)
__device__ __forceinline__ unsigned short f2bf(float x) {
    unsigned int u = __float_as_uint(x);
    return (unsigned short)((u + 0x7fffu + ((u >> 16) & 1u)) >> 16);
}
// bf16 pair (packed in uint) -> floats
__device__ __forceinline__ float bflo(unsigned int v) { return __uint_as_float(v << 16); }
__device__ __forceinline__ float bfhi(unsigned int v) { return __uint_as_float(v & 0xFFFF0000u); }

__device__ __forceinline__ bf16x8 pack8(float4 a, float4 b) {
    union { unsigned short u[8]; bf16x8 v; } p;
    p.u[0] = f2bf(a.x); p.u[1] = f2bf(a.y); p.u[2] = f2bf(a.z); p.u[3] = f2bf(a.w);
    p.u[4] = f2bf(b.x); p.u[5] = f2bf(b.y); p.u[6] = f2bf(b.z); p.u[7] = f2bf(b.w);
    return p.v;
}

// Block-wide sum of (a,b). blockDim.x == 256.
__device__ __forceinline__ float2 block_reduce_sum2(float a, float b) {
    #pragma unroll
    for (int off = 1; off < 64; off <<= 1) {
        a += __shfl_xor(a, off, 64);
        b += __shfl_xor(b, off, 64);
    }
    __shared__ float lds[8];
    const int t = threadIdx.x;
    if ((t & 63) == 0) { lds[2 * (t >> 6)] = a; lds[2 * (t >> 6) + 1] = b; }
    __syncthreads();
    a = lds[0] + lds[2] + lds[4] + lds[6];
    b = lds[1] + lds[3] + lds[5] + lds[7];
    return make_float2(a, b);
}

// ---------------- K1: conv1(3->16) + IN + lrelu, single pass, bf16 out -----------
// grid: B=256 blocks, 1024 threads, 4 px/thread, acc[16][4] in VGPRs.
__global__ __launch_bounds__(1024, 1) void k1_conv_in(const float* __restrict__ x,
                                                      const float* __restrict__ w1,
                                                      unsigned short* __restrict__ h1) {
    const int n = blockIdx.x;
    const int t = threadIdx.x;
    __shared__ float red[16][16][2]; // [wave][co][s1/s2]
    __shared__ float msc[16][2];     // [co][mean/scale]
    const float* xn = x + (size_t)n * 49152;
    float acc[16][4];
    #pragma unroll
    for (int j = 0; j < 16; ++j)
        #pragma unroll
        for (int q = 0; q < 4; ++q) acc[j][q] = 0.f;
    #pragma unroll 1
    for (int ic = 0; ic < 3; ++ic) {
        const float* p = xn + ic * 16384;
        float2 v0[4], v1[4];
        #pragma unroll
        for (int q = 0; q < 4; ++q) {
            const int idx = t + 1024 * q;
            const int oy = idx >> 6, ox = idx & 63;
            v0[q] = ((const float2*)(p + (2 * oy) * 128))[ox];
            v1[q] = ((const float2*)(p + (2 * oy + 1) * 128))[ox];
        }
        #pragma unroll
        for (int j = 0; j < 16; ++j) {
            const float4 wv = *(const float4*)(w1 + j * 12 + ic * 4);  // uniform -> SGPR
            #pragma unroll
            for (int q = 0; q < 4; ++q)
                acc[j][q] += v0[q].x * wv.x + v0[q].y * wv.y + v1[q].x * wv.z + v1[q].y * wv.w;
        }
    }
    const int w = t >> 6, l = t & 63;
    #pragma unroll
    for (int j = 0; j < 16; ++j) {
        float s1 = acc[j][0] + acc[j][1] + acc[j][2] + acc[j][3];
        float s2 = acc[j][0] * acc[j][0] + acc[j][1] * acc[j][1] +
                   acc[j][2] * acc[j][2] + acc[j][3] * acc[j][3];
        #pragma unroll
        for (int off = 1; off < 64; off <<= 1) {
            s1 += __shfl_xor(s1, off, 64);
            s2 += __shfl_xor(s2, off, 64);
        }
        if (l == 0) { red[w][j][0] = s1; red[w][j][1] = s2; }
    }
    __syncthreads();
    if (t < 16) {
        float s1 = 0.f, s2 = 0.f;
        #pragma unroll
        for (int ww = 0; ww < 16; ++ww) { s1 += red[ww][t][0]; s2 += red[ww][t][1]; }
        const float mean = s1 * (1.f / 4096.f);
        const float var = s2 * (1.f / 4096.f) - mean * mean;
        msc[t][0] = mean; msc[t][1] = rsqrtf(var + EPSI);
    }
    __syncthreads();
    unsigned short* on = h1 + (size_t)n * 65536;
    #pragma unroll
    for (int j = 0; j < 16; ++j) {
        const float mean = msc[j][0], sc = msc[j][1];
        #pragma unroll
        for (int q = 0; q < 4; ++q)
            on[j * 4096 + t + 1024 * q] = f2bf(lrelu((acc[j][q] - mean) * sc));
    }
}

// ---------------- K2: conv2(16->32) + IN + lrelu, (n, 16co) blocks ---------------
// grid: B*2 = 512 blocks, 512 threads, 2 px/thread, acc[16][2]. Global bf16 reads;
// h1 (33.5MB) is L3-resident, 2x redundancy is cheap. Weights uniform -> SGPR.
__global__ __launch_bounds__(512, 2) void k2_conv_in(const unsigned short* __restrict__ h1,
                                                     const float* __restrict__ w2,
                                                     unsigned short* __restrict__ h2) {
    const int n = blockIdx.x >> 1, cg = blockIdx.x & 1;
    const int t = threadIdx.x;
    __shared__ float red[8][16][2];
    __shared__ float msc[16][2];
    const unsigned short* h1n = h1 + (size_t)n * 65536;
    const int oy0 = t >> 5, ox0 = t & 31;            // px t
    const int oy1 = oy0 + 16;                        // px t+512
    float acc[16][2];
    #pragma unroll
    for (int j = 0; j < 16; ++j) { acc[j][0] = 0.f; acc[j][1] = 0.f; }
    #pragma unroll 1
    for (int ic = 0; ic < 16; ++ic) {
        const unsigned short* pl = h1n + ic * 4096;
        const unsigned int a0 = *(const unsigned int*)(pl + (2 * oy0) * 64 + 2 * ox0);
        const unsigned int a1 = *(const unsigned int*)(pl + (2 * oy0 + 1) * 64 + 2 * ox0);
        const unsigned int b0 = *(const unsigned int*)(pl + (2 * oy1) * 64 + 2 * ox0);
        const unsigned int b1 = *(const unsigned int*)(pl + (2 * oy1 + 1) * 64 + 2 * ox0);
        const float f00 = bflo(a0), f01 = bfhi(a0), f02 = bflo(a1), f03 = bfhi(a1);
        const float f10 = bflo(b0), f11 = bfhi(b0), f12 = bflo(b1), f13 = bfhi(b1);
        #pragma unroll
        for (int j = 0; j < 16; ++j) {
            const float4 wv = *(const float4*)(w2 + (cg * 16 + j) * 144 + ic * 4);  // SGPR
            acc[j][0] += f00 * wv.x + f01 * wv.y + f02 * wv.z + f03 * wv.w;
            acc[j][1] += f10 * wv.x + f11 * wv.y + f12 * wv.z + f13 * wv.w;
        }
    }
    const int w = t >> 6, l = t & 63;
    #pragma unroll
    for (int j = 0; j < 16; ++j) {
        float s1 = acc[j][0] + acc[j][1];
        float s2 = acc[j][0] * acc[j][0] + acc[j][1] * acc[j][1];
        #pragma unroll
        for (int off = 1; off < 64; off <<= 1) {
            s1 += __shfl_xor(s1, off, 64);
            s2 += __shfl_xor(s2, off, 64);
        }
        if (l == 0) { red[w][j][0] = s1; red[w][j][1] = s2; }
    }
    __syncthreads();
    if (t < 16) {
        float s1 = 0.f, s2 = 0.f;
        #pragma unroll
        for (int ww = 0; ww < 8; ++ww) { s1 += red[ww][t][0]; s2 += red[ww][t][1]; }
        const float mean = s1 * (1.f / 1024.f);
        const float var = s2 * (1.f / 1024.f) - mean * mean;
        msc[t][0] = mean; msc[t][1] = rsqrtf(var + EPSI);
    }
    __syncthreads();
    unsigned short* on = h2 + (size_t)n * 32768 + cg * 16384;
    #pragma unroll
    for (int j = 0; j < 16; ++j) {
        const float mean = msc[j][0], sc = msc[j][1];
        on[j * 1024 + t]       = f2bf(lrelu((acc[j][0] - mean) * sc));
        on[j * 1024 + t + 512] = f2bf(lrelu((acc[j][1] - mean) * sc));
    }
}

// ---------------- K3: conv3(32->64) + IN + lrelu, (n, 16co) blocks ---------------
// grid: B*4 = 1024 blocks (4/CU, 16 waves/CU), 256 threads, 1 px/thread, acc[16].
__global__ __launch_bounds__(256, 4) void k3_conv_in(const unsigned short* __restrict__ h2,
                                                     const float* __restrict__ w3,
                                                     unsigned short* __restrict__ h3) {
    const int n = blockIdx.x >> 2, cg = blockIdx.x & 3;
    const int t = threadIdx.x;
    __shared__ float red[4][16][2];
    __shared__ float msc[16][2];
    const unsigned short* h2n = h2 + (size_t)n * 32768;
    const int oy = t >> 4, ox = t & 15;
    float acc[16];
    #pragma unroll
    for (int j = 0; j < 16; ++j) acc[j] = 0.f;
    #pragma unroll 1
    for (int ic = 0; ic < 32; ++ic) {
        const unsigned short* pl = h2n + ic * 1024;
        const unsigned int a0 = *(const unsigned int*)(pl + (2 * oy) * 32 + 2 * ox);
        const unsigned int a1 = *(const unsigned int*)(pl + (2 * oy + 1) * 32 + 2 * ox);
        const float f0 = bflo(a0), f1 = bfhi(a0), f2 = bflo(a1), f3 = bfhi(a1);
        #pragma unroll
        for (int j = 0; j < 16; ++j) {
            const float4 wv = *(const float4*)(w3 + (size_t)(cg * 16 + j) * 128 + ic * 4);  // SGPR
            acc[j] += f0 * wv.x + f1 * wv.y + f2 * wv.z + f3 * wv.w;
        }
    }
    const int w = t >> 6, l = t & 63;
    #pragma unroll
    for (int j = 0; j < 16; ++j) {
        float s1 = acc[j], s2 = acc[j] * acc[j];
        #pragma unroll
        for (int off = 1; off < 64; off <<= 1) {
            s1 += __shfl_xor(s1, off, 64);
            s2 += __shfl_xor(s2, off, 64);
        }
        if (l == 0) { red[w][j][0] = s1; red[w][j][1] = s2; }
    }
    __syncthreads();
    if (t < 16) {
        const float s1 = red[0][t][0] + red[1][t][0] + red[2][t][0] + red[3][t][0];
        const float s2 = red[0][t][1] + red[1][t][1] + red[2][t][1] + red[3][t][1];
        const float mean = s1 * (1.f / 256.f);
        const float var = s2 * (1.f / 256.f) - mean * mean;
        msc[t][0] = mean; msc[t][1] = rsqrtf(var + EPSI);
    }
    __syncthreads();
    unsigned short* on = h3 + (size_t)n * 16384 + cg * 4096;
    #pragma unroll
    for (int j = 0; j < 16; ++j)
        on[j * 256 + t] = f2bf(lrelu((acc[j] - msc[j][0]) * msc[j][1]));
}

// ---------------- K4: conv4(64->128) + IN + lrelu, (n, 32co) blocks --------------
// grid: B*4 = 1024 blocks, 256 threads (4 waves). Wave w: 8 co, lane = px (8x8).
// IN reduce = pure wave shuffle (plane == 64 lanes). Weights wave-uniform -> SGPR.
__global__ __launch_bounds__(256, 4) void k4_conv_in(const unsigned short* __restrict__ h3,
                                                     const float* __restrict__ w4,
                                                     unsigned short* __restrict__ h4) {
    const int n = blockIdx.x >> 2, cg = blockIdx.x & 3;
    const int t = threadIdx.x;
    const int w = __builtin_amdgcn_readfirstlane(t >> 6);
    const int l = t & 63;
    const int oy = l >> 3, ox = l & 7;
    const unsigned short* h3n = h3 + (size_t)n * 16384;
    const float* wbase = w4 + (size_t)(cg * 32 + w * 8) * 256;
    float acc[8];
    #pragma unroll
    for (int jj = 0; jj < 8; ++jj) acc[jj] = 0.f;
    #pragma unroll 1
    for (int ic = 0; ic < 64; ++ic) {
        const unsigned short* pl = h3n + ic * 256;
        const unsigned int a0 = *(const unsigned int*)(pl + (2 * oy) * 16 + 2 * ox);
        const unsigned int a1 = *(const unsigned int*)(pl + (2 * oy + 1) * 16 + 2 * ox);
        const float f0 = bflo(a0), f1 = bfhi(a0), f2 = bflo(a1), f3 = bfhi(a1);
        #pragma unroll
        for (int jj = 0; jj < 8; ++jj) {
            const float4 wv = *(const float4*)(wbase + jj * 256 + ic * 4);  // SGPR
            acc[jj] += f0 * wv.x + f1 * wv.y + f2 * wv.z + f3 * wv.w;
        }
    }
    unsigned short* on = h4 + (size_t)n * 8192;
    #pragma unroll
    for (int jj = 0; jj < 8; ++jj) {
        float s1 = acc[jj], s2 = acc[jj] * acc[jj];
        #pragma unroll
        for (int off = 1; off < 64; off <<= 1) {
            s1 += __shfl_xor(s1, off, 64);
            s2 += __shfl_xor(s2, off, 64);
        }
        const float mean = s1 * (1.f / 64.f);
        const float var = s2 * (1.f / 64.f) - mean * mean;
        const float sc = rsqrtf(var + EPSI);
        on[(cg * 32 + w * 8 + jj) * 64 + l] = f2bf(lrelu((acc[jj] - mean) * sc));
    }
}

// ---------------- K5: FC1 bf16 MFMA split-K GEMM (W converted in-staging) --------
// C[256,1024] = A[256,8192](bf16) x W[1024,8192]^T(fp32->bf16 on the fly).
// BM=BN=128, BK=64, SK=16 (K-chunk 512): grid = 16 tiles x 16 sk = 256 blocks.
__global__ __launch_bounds__(256, 2) void k5_fc1(const unsigned short* __restrict__ A,
                                                 const float* __restrict__ Wf,
                                                 float* __restrict__ Cp) {
    __shared__ unsigned short As[128 * 72];
    __shared__ unsigned short Bs[128 * 72];
    const int t = threadIdx.x;
    const int sk = blockIdx.x >> 4;          // 0..15
    const int tile = blockIdx.x & 15;        // mt*8 + nt
    const int mt = tile >> 3, nt = tile & 7;
    const int m0 = mt * 128, n0 = nt * 128;
    const int w = t >> 6, l = t & 63;
    const int wm = (w >> 1) * 64, wn = (w & 1) * 64;
    const int lr16 = l & 15, lk8 = (l >> 4) * 8;   // frag row / k-base (guide §3)
    const int srow = t >> 3, scol = (t & 7) * 8;   // staging row / col
    f32x4 acc[4][4];
    const f32x4 z = {0.f, 0.f, 0.f, 0.f};
    #pragma unroll
    for (int f = 0; f < 4; ++f)
        #pragma unroll
        for (int g = 0; g < 4; ++g) acc[f][g] = z;
    const int kbeg = sk * 512;
    #pragma unroll 1
    for (int kt = 0; kt < 8; ++kt) {
        const int kc = kbeg + kt * 64;
        bf16x8 av[4], bv[4];
        #pragma unroll
        for (int i = 0; i < 4; ++i) {
            av[i] = *(const bf16x8*)(A + (size_t)(m0 + srow + 32 * i) * 8192 + kc + scol);
            const float4 w0 = *(const float4*)(Wf + (size_t)(n0 + srow + 32 * i) * 8192 + kc + scol);
            const float4 w1 = *(const float4*)(Wf + (size_t)(n0 + srow + 32 * i) * 8192 + kc + scol + 4);
            bv[i] = pack8(w0, w1);
        }
        __syncthreads();   // previous tile's frag reads complete
        #pragma unroll
        for (int i = 0; i < 4; ++i) {
            *(bf16x8*)&As[(srow + 32 * i) * 72 + scol] = av[i];
            *(bf16x8*)&Bs[(srow + 32 * i) * 72 + scol] = bv[i];
        }
        __syncthreads();   // tile staged
        #pragma unroll
        for (int ks = 0; ks < 2; ++ks) {
            bf16x8 af[4], bfr[4];
            #pragma unroll
            for (int f = 0; f < 4; ++f)
                af[f] = *(const bf16x8*)&As[(wm + f * 16 + lr16) * 72 + ks * 32 + lk8];
            #pragma unroll
            for (int g = 0; g < 4; ++g)
                bfr[g] = *(const bf16x8*)&Bs[(wn + g * 16 + lr16) * 72 + ks * 32 + lk8];
            #pragma unroll
            for (int f = 0; f < 4; ++f)
                #pragma unroll
                for (int g = 0; g < 4; ++g)
                    acc[f][g] = __builtin_amdgcn_mfma_f32_16x16x32_bf16(af[f], bfr[g], acc[f][g], 0, 0, 0);
        }
    }
    // C/D layout (guide §3, m89-verified): col = l&15, row = (l>>4)*4 + reg
    const int orow = (l >> 4) * 4, ocol = l & 15;
    #pragma unroll
    for (int f = 0; f < 4; ++f) {
        #pragma unroll
        for (int g = 0; g < 4; ++g) {
            #pragma unroll
            for (int j = 0; j < 4; ++j) {
                const int m = m0 + wm + f * 16 + orow + j;
                const int n = n0 + wn + g * 16 + ocol;
                Cp[((size_t)sk * 256 + m) * 1024 + n] = acc[f][g][j];
            }
        }
    }
}

// ---------------- K6: fused split-K reduce + bias + lrelu + FC2 ------------------
__global__ __launch_bounds__(256) void k6_fc2(const float* __restrict__ Cp,
                                              const float* __restrict__ bias,
                                              const float* __restrict__ w,
                                              const float* __restrict__ b,
                                              float* __restrict__ out) {
    const int n = blockIdx.x, t = threadIdx.x;
    float part = 0.f;
    #pragma unroll
    for (int i = 0; i < 4; ++i) {
        const int nn = t + 256 * i;
        float s = 0.f;
        #pragma unroll
        for (int sk = 0; sk < 16; ++sk)
            s += Cp[((size_t)sk * 256 + n) * 1024 + nn];
        part += lrelu(s + bias[nn]) * w[nn];
    }
    const float2 red = block_reduce_sum2(part, 0.f);
    if (t == 0) out[n] = red.x + b[0];
}

extern "C" void kernel_launch(void* const* d_in, const int* in_sizes, int n_in,
                              void* d_out, int out_size, void* d_ws, size_t ws_size,
                              hipStream_t stream) {
    (void)in_sizes; (void)n_in; (void)out_size; (void)ws_size;
    const float* x    = (const float*)d_in[0];
    // labels (d_in[1]) and conv biases (d_in[3,5,7,9]) cancel exactly under InstanceNorm
    const float* w1   = (const float*)d_in[2];
    const float* w2   = (const float*)d_in[4];
    const float* w3   = (const float*)d_in[6];
    const float* w4   = (const float*)d_in[8];
    const float* fcw1 = (const float*)d_in[10];
    const float* fcb1 = (const float*)d_in[11];
    const float* fcw2 = (const float*)d_in[12];
    const float* fcb2 = (const float*)d_in[13];
    float* out = (float*)d_out;
    float* bufA = (float*)d_ws;                    // 16.7M floats (67 MB)
    float* bufB = bufA + 16777216;                 //  8.4M floats (33 MB)
    unsigned short* h1 = (unsigned short*)bufA;    // 16.7M bf16 (33.5 MB)
    unsigned short* h2 = (unsigned short*)bufB;    //  8.4M bf16 (16.8 MB)
    unsigned short* h3 = (unsigned short*)bufA;    //  4.2M bf16 (h1 dead)
    unsigned short* h4 = (unsigned short*)bufB;    //  2.1M bf16 (h2 dead)
    float* Cp = bufA;                              // 16*256*1024 fp32 (h3 dead at k5)
    k1_conv_in<<<256, 1024, 0, stream>>>(x, w1, h1);
    k2_conv_in<<<512, 512, 0, stream>>>(h1, w2, h2);
    k3_conv_in<<<1024, 256, 0, stream>>>(h2, w3, h3);
    k4_conv_in<<<1024, 256, 0, stream>>>(h3, w4, h4);
    k5_fc1<<<256, 256, 0, stream>>>(h4, fcw1, Cp);
    k6_fc2<<<256, 256, 0, stream>>>(Cp, fcb1, fcw2, fcb2, out);
}